// Round 3
// baseline (18027.856 us; speedup 1.0000x reference)
//
#include <hip/hip_runtime.h>
#include <math.h>

typedef unsigned short u16;
typedef short s8v __attribute__((ext_vector_type(8)));    // 8 bf16 (MFMA A/B frag)
typedef float f4v __attribute__((ext_vector_type(4)));    // MFMA C/D frag

constexpr int cH  = 256;
constexpr int cS  = 64;
constexpr int cAN = 16;
constexpr int cT  = 32;
constexpr int cN  = 64;
constexpr int cHG = 770;
constexpr int cG3 = 2310;
constexpr int cOW = 338;
constexpr int GRID = 256;
constexpr int CK   = 112;   // GRU k-chunk
constexpr int NCH  = 7;     // ceil(784/112)
constexpr int HTROWS = 196; // hT rows (k/4 groups, padded)

union Sh {
  struct { float4 hsT[28][64]; } gru;                                   // 28.7 KB
  struct { u16 a[64 * 264]; u16 b[64 * 264]; } ge;                      // 67.6 KB
  struct { float rs[256]; float bs[512]; float wt[32][260]; float w0s[32][12]; } c0;
  struct { float ss[256]; float es[256]; float red[256];
           float lg[16]; float dpv[16]; float nz[16]; float pr[16];
           float pss[64]; float red64[64]; float mxs[2]; int anynz; } tl;
};

__device__ __forceinline__ u16 f2bf(float x) {
  unsigned u = __float_as_uint(x);
  unsigned r = (u + 0x7FFFu + ((u >> 16) & 1u)) >> 16;
  return (u16)r;
}

// Distributed grid barrier: per-block arrival lines + single release line.
__device__ __forceinline__ void gbar(int* arv, int* rel, int ph) {
  __syncthreads();
  if (blockIdx.x == 0) {
    if (threadIdx.x > 0 && threadIdx.x < GRID) {
      while (__hip_atomic_load(&arv[threadIdx.x * 32], __ATOMIC_ACQUIRE,
                               __HIP_MEMORY_SCOPE_AGENT) < ph)
        __builtin_amdgcn_s_sleep(1);
    }
    __syncthreads();
    if (threadIdx.x == 0)
      __hip_atomic_store(rel, ph, __ATOMIC_RELEASE, __HIP_MEMORY_SCOPE_AGENT);
  } else {
    if (threadIdx.x == 0) {
      __hip_atomic_store(&arv[blockIdx.x * 32], ph, __ATOMIC_RELEASE,
                         __HIP_MEMORY_SCOPE_AGENT);
      while (__hip_atomic_load(rel, __ATOMIC_ACQUIRE,
                               __HIP_MEMORY_SCOPE_AGENT) < ph)
        __builtin_amdgcn_s_sleep(1);
    }
  }
  __syncthreads();
}

// softmax(p[n]) -> psb, r[n] = ps @ M[n]
__device__ __forceinline__ void ps_r_compute(int n, const float* p, const float* X,
                                             float* psb, float* r,
                                             float* pss, float* red, float* mxs) {
  int tid = threadIdx.x;
  if (tid < cS) red[tid] = p[n * cS + tid];
  __syncthreads();
  if (tid == 0) { float m = red[0]; for (int i = 1; i < cS; ++i) m = fmaxf(m, red[i]); mxs[0] = m; }
  __syncthreads();
  if (tid < cS) red[tid] = expf(red[tid] - mxs[0]);
  __syncthreads();
  if (tid == 0) { float s = 0.f; for (int i = 0; i < cS; ++i) s += red[i]; mxs[1] = s; }
  __syncthreads();
  if (tid < cS) { pss[tid] = red[tid] / mxs[1]; psb[n * cS + tid] = pss[tid]; }
  __syncthreads();
  float acc = 0.f;
  for (int s2 = 0; s2 < cS; ++s2)
    acc += pss[s2] * X[((size_t)(n * cS + s2)) * cHG + 2 + tid];
  r[n * cH + tid] = acc;
}

// 64x64x256 bf16 MFMA tile: stages A,B rows (K contiguous) then 8 k-steps.
__device__ __forceinline__ void mfma_block_gemm(const u16* Ab, size_t lda,
                                                const u16* Bb, size_t ldb,
                                                u16* AsL, u16* BsL, int tid,
                                                f4v acc[2][2]) {
  #pragma unroll
  for (int q = 0; q < 8; ++q) {
    int idx = q * 256 + tid, row = idx >> 5, c = idx & 31;
    *(s8v*)&AsL[row * 264 + c * 8] = *(const s8v*)(Ab + (size_t)row * lda + c * 8);
    *(s8v*)&BsL[row * 264 + c * 8] = *(const s8v*)(Bb + (size_t)row * ldb + c * 8);
  }
  __syncthreads();
  int lane = tid & 63, wv = tid >> 6;
  int mt = (wv & 1) << 5, nt = (wv >> 1) << 5;
  int fr = lane & 15, kg = (lane >> 4) << 3;
  #pragma unroll
  for (int ks = 0; ks < 8; ++ks) {
    int ko = ks * 32 + kg;
    s8v a0 = *(const s8v*)&AsL[(mt + fr) * 264 + ko];
    s8v a1 = *(const s8v*)&AsL[(mt + 16 + fr) * 264 + ko];
    s8v b0 = *(const s8v*)&BsL[(nt + fr) * 264 + ko];
    s8v b1 = *(const s8v*)&BsL[(nt + 16 + fr) * 264 + ko];
    acc[0][0] = __builtin_amdgcn_mfma_f32_16x16x32_bf16(a0, b0, acc[0][0], 0, 0, 0);
    acc[0][1] = __builtin_amdgcn_mfma_f32_16x16x32_bf16(a0, b1, acc[0][1], 0, 0, 0);
    acc[1][0] = __builtin_amdgcn_mfma_f32_16x16x32_bf16(a1, b0, acc[1][0], 0, 0, 0);
    acc[1][1] = __builtin_amdgcn_mfma_f32_16x16x32_bf16(a1, b1, acc[1][1], 0, 0, 0);
  }
}

__global__ __launch_bounds__(256, 2) void k_fused(
    const float* __restrict__ base, const float* __restrict__ inter,
    const float* __restrict__ hxs, const float* __restrict__ emb,
    const float* __restrict__ w_ih, const float* __restrict__ w_hh,
    const float* __restrict__ b_ih, const float* __restrict__ b_hh,
    const float* __restrict__ conv0_w, const float* __restrict__ conv0_b,
    const float* __restrict__ convs_w, const float* __restrict__ convs_b,
    const float* __restrict__ lin_w, const float* __restrict__ lin_b,
    const float* __restrict__ psi_w, const float* __restrict__ psi_b,
    const float* __restrict__ actor_w, const float* __restrict__ actor_b,
    const float* __restrict__ critic_w, const float* __restrict__ critic_b,
    const int* __restrict__ subtasks, const int* __restrict__ actions,
    float* __restrict__ out,
    int* arv, int* rel,
    float* __restrict__ gitab, float* __restrict__ X, float* __restrict__ hT,
    float* __restrict__ psip,
    float* __restrict__ p, float* __restrict__ psb, float* __restrict__ r,
    float* __restrict__ nMp, float* __restrict__ nMm,
    float* __restrict__ part,
    u16* __restrict__ w1b, u16* __restrict__ w2b, u16* __restrict__ linb,
    u16* __restrict__ x1b, u16* __restrict__ x2b, u16* __restrict__ x3tb) {
  __shared__ Sh sh;
  const int bid = blockIdx.x, tid = threadIdx.x;
  int ph = 0;

  // ---------------- phase 0: gitab, psip, bf16 weight converts ----------------
  for (int work = bid; work < 320; work += GRID) {
    int v = work / 10, jb = work % 10;
    int j = jb * 256 + tid;
    if (j < cG3) {
      float acc = b_ih[j];
      const float* wr = w_ih + (size_t)j * cH;
      const float* er = emb + (size_t)v * cH;
      #pragma unroll 8
      for (int h = 0; h < cH; ++h) acc += wr[h] * er[h];
      gitab[(size_t)v * cG3 + j] = acc;
    }
  }
  #pragma unroll
  for (int q = 0; q < 16; ++q) {
    int idx = bid * 4096 + q * 256 + tid;
    int a = idx >> 16, h = (idx >> 8) & 255, o = idx & 255;
    psip[idx] = psi_w[((size_t)o * cH + h) * cAN + a];
  }
  for (int i = bid * 256 + tid; i < 131072; i += GRID * 256) {
    w1b[i] = f2bf(convs_w[i]);  // w2b = w1b + 65536 contiguity handled below
  }
  for (int i = bid * 256 + tid; i < 131072; i += GRID * 256) {
    if (i >= 65536) w2b[i - 65536] = f2bf(convs_w[i]);
  }
  for (int it = 0; it < 64; ++it) {
    size_t i = (size_t)bid * 16384 + it * 256 + tid;
    linb[i] = f2bf(lin_w[i]);
  }
  gbar(arv, rel, ++ph);

  // ---------------- phase 1: GRU (weights via scalar loads, hsT conflict-free) ---
  {
    int m = tid & 63;
    int klu = __builtin_amdgcn_readfirstlane(tid >> 6);   // wave-uniform
    int krow = bid * 4 + klu;
    bool act = (bid < 193) && (krow < cHG);
    int krs = (krow < cHG) ? krow : 0;
    const float* w0 = w_hh + (size_t)krs * cHG;
    const float* w1 = w_hh + (size_t)(cHG + krs) * cHG;
    const float* w2 = w_hh + (size_t)(2 * cHG + krs) * cHG;
    for (int s = 0; s < cS; ++s) {
      float accr = 0.f, accz = 0.f, accn = 0.f;
      if (bid < 193 && s > 0) {
        const float4* hTr = (const float4*)(hT + (size_t)((s - 1) & 1) * (HTROWS * 64 * 4));
        for (int c = 0; c < NCH; ++c) {
          #pragma unroll
          for (int q = 0; q < 7; ++q) {
            int idx = q * 256 + tid;
            int j = idx >> 6, mm = idx & 63;
            sh.gru.hsT[j][mm] = hTr[(c * 28 + j) * 64 + mm];
          }
          __syncthreads();
          int kc = c * CK;
          if (c < 6) {
            #pragma unroll 7
            for (int j = 0; j < 28; ++j) {
              float4 h4 = sh.gru.hsT[j][m];
              float4 w0v = *(const float4*)(w0 + kc + 4 * j);
              float4 w1v = *(const float4*)(w1 + kc + 4 * j);
              float4 w2v = *(const float4*)(w2 + kc + 4 * j);
              accr += h4.x * w0v.x + h4.y * w0v.y + h4.z * w0v.z + h4.w * w0v.w;
              accz += h4.x * w1v.x + h4.y * w1v.y + h4.z * w1v.z + h4.w * w1v.w;
              accn += h4.x * w2v.x + h4.y * w2v.y + h4.z * w2v.z + h4.w * w2v.w;
            }
          } else {
            #pragma unroll 6
            for (int j = 0; j < 24; ++j) {      // k 672..767
              float4 h4 = sh.gru.hsT[j][m];
              float4 w0v = *(const float4*)(w0 + kc + 4 * j);
              float4 w1v = *(const float4*)(w1 + kc + 4 * j);
              float4 w2v = *(const float4*)(w2 + kc + 4 * j);
              accr += h4.x * w0v.x + h4.y * w0v.y + h4.z * w0v.z + h4.w * w0v.w;
              accz += h4.x * w1v.x + h4.y * w1v.y + h4.z * w1v.z + h4.w * w1v.w;
              accn += h4.x * w2v.x + h4.y * w2v.y + h4.z * w2v.z + h4.w * w2v.w;
            }
            float4 h4 = sh.gru.hsT[24][m];       // k 768, 769
            accr += h4.x * w0[768] + h4.y * w0[769];
            accz += h4.x * w1[768] + h4.y * w1[769];
            accn += h4.x * w2[768] + h4.y * w2[769];
          }
          __syncthreads();
        }
      }
      if (act) {
        int v = subtasks[m * cS + s];
        const float* git = gitab + (size_t)v * cG3;
        float rg = 1.f / (1.f + expf(-(git[krow] + accr + b_hh[krow])));
        float zg = 1.f / (1.f + expf(-(git[cHG + krow] + accz + b_hh[cHG + krow])));
        float ng = tanhf(git[2 * cHG + krow] + rg * (accn + b_hh[2 * cHG + krow]));
        float hp = (s > 0) ? X[((size_t)(m * cS + s - 1)) * cHG + krow] : 0.f;
        float h2 = (1.f - zg) * ng + zg * hp;
        X[((size_t)(m * cS + s)) * cHG + krow] = h2;
        hT[(size_t)(s & 1) * (HTROWS * 64 * 4) + ((krow >> 2) * 64 + m) * 4 + (krow & 3)] = h2;
      }
      gbar(arv, rel, ++ph);
    }
  }

  // ---------------- phase 2: p_init, norms, ps0/r0 ----------------
  if (bid < cN) {
    int n = bid;
    if (tid == 0) sh.tl.anynz = 0;
    __syncthreads();
    int nz = (hxs[n * cOW + tid] != 0.f) ? 1 : 0;
    if (tid + 256 < cOW) nz |= (hxs[n * cOW + tid + 256] != 0.f) ? 1 : 0;
    if (nz) sh.tl.anynz = 1;
    __syncthreads();
    bool newep = (sh.tl.anynz == 0);
    if (tid < cS) {
      const float* xr = X + ((size_t)(n * cS + tid)) * cHG;
      float p0 = xr[1];
      p[n * cS + tid] = newep ? p0 : hxs[n * cOW + 1 + cAN + 1 + cH + tid];
      float sp = 0.f, sm = 0.f;
      for (int h = 0; h < cH; ++h) {
        float vp = xr[2 + 2 * cH + h]; sp += vp * vp;
        float vm = xr[2 + cH + h];     sm += vm * vm;
      }
      nMp[n * cS + tid] = sqrtf(sp);
      nMm[n * cS + tid] = sqrtf(sm);
    }
    __syncthreads();
    ps_r_compute(n, p, X, psb, r, sh.tl.pss, sh.tl.red64, sh.tl.mxs);
  }
  gbar(arv, rel, ++ph);

  // ---------------- phase 3: T-scan ----------------
  for (int t = 0; t < cT; ++t) {
    // ---- conv0 (factorized, fp32 compute, bf16 output) ----
    {
      int obq = bid >> 6, n = bid & 63;
      sh.c0.rs[tid] = r[n * cH + tid];
      sh.c0.bs[tid]       = base[((size_t)(t * cN + n)) * 512 + tid];
      sh.c0.bs[tid + 256] = base[((size_t)(t * cN + n)) * 512 + tid + 256];
      __syncthreads();
      for (int half = 0; half < 2; ++half) {
        int ob = obq * 2 + half;
        int o_l = tid >> 3, d = tid & 7;
        float acc = 0.f;
        for (int hc = 0; hc < 8; ++hc) {
          #pragma unroll
          for (int q = 0; q < 8; ++q) {
            int idx = q * 256 + tid;
            int row = idx >> 6, c4 = (idx & 63) * 4;
            *(float4*)&sh.c0.wt[row][c4] =
                *(const float4*)(conv0_w + (size_t)(ob * 32 + row) * 2048 + hc * 256 + c4);
          }
          __syncthreads();
          #pragma unroll
          for (int h2 = 0; h2 < 32; ++h2)
            acc += sh.c0.wt[o_l][h2 * 8 + d] * sh.c0.rs[hc * 32 + h2];
          __syncthreads();
        }
        sh.c0.w0s[o_l][d] = acc;
        __syncthreads();
        int o2 = tid & 31, ijg = tid >> 5;
        float bias = conv0_b[ob * 32 + o2];
        #pragma unroll
        for (int q = 0; q < 8; ++q) {
          int ij = ijg * 8 + q;
          float v = bias;
          #pragma unroll
          for (int d2 = 0; d2 < 8; ++d2) v += sh.c0.w0s[o2][d2] * sh.c0.bs[d2 * 64 + ij];
          x1b[((size_t)(n * 64 + ij)) * cH + ob * 32 + o2] = f2bf(fmaxf(v, 0.f));
        }
        __syncthreads();
      }
    }
    gbar(arv, rel, ++ph);

    // ---- x2 = relu(x1 @ W1^T + b1)  [MFMA] ----
    {
      f4v acc[2][2];
      #pragma unroll
      for (int i = 0; i < 2; ++i)
        #pragma unroll
        for (int j = 0; j < 2; ++j) acc[i][j] = (f4v){0.f, 0.f, 0.f, 0.f};
      mfma_block_gemm(x1b + (size_t)(bid >> 2) * 64 * 256, 256,
                      w1b + (size_t)(bid & 3) * 64 * 256, 256,
                      sh.ge.a, sh.ge.b, tid, acc);
      int lane = tid & 63, wv = tid >> 6;
      int mt = (wv & 1) << 5, nt = (wv >> 1) << 5;
      int fr = lane & 15, r4 = (lane >> 4) << 2;
      #pragma unroll
      for (int mi = 0; mi < 2; ++mi)
        #pragma unroll
        for (int ni = 0; ni < 2; ++ni) {
          int col = (bid & 3) * 64 + nt + ni * 16 + fr;
          float bv = convs_b[col];
          #pragma unroll
          for (int rr = 0; rr < 4; ++rr) {
            int row = (bid >> 2) * 64 + mt + mi * 16 + r4 + rr;
            x2b[(size_t)row * 256 + col] = f2bf(fmaxf(acc[mi][ni][rr] + bv, 0.f));
          }
        }
    }
    gbar(arv, rel, ++ph);

    // ---- x3t = relu(x2 @ W2^T + b2), transposed write  [MFMA] ----
    {
      f4v acc[2][2];
      #pragma unroll
      for (int i = 0; i < 2; ++i)
        #pragma unroll
        for (int j = 0; j < 2; ++j) acc[i][j] = (f4v){0.f, 0.f, 0.f, 0.f};
      mfma_block_gemm(x2b + (size_t)(bid >> 2) * 64 * 256, 256,
                      w2b + (size_t)(bid & 3) * 64 * 256, 256,
                      sh.ge.a, sh.ge.b, tid, acc);
      int lane = tid & 63, wv = tid >> 6;
      int mt = (wv & 1) << 5, nt = (wv >> 1) << 5;
      int fr = lane & 15, r4 = (lane >> 4) << 2;
      #pragma unroll
      for (int mi = 0; mi < 2; ++mi)
        #pragma unroll
        for (int ni = 0; ni < 2; ++ni) {
          int o = (bid & 3) * 64 + nt + ni * 16 + fr;
          float bv = convs_b[256 + o];
          #pragma unroll
          for (int rr = 0; rr < 4; ++rr) {
            int ij = mt + mi * 16 + r4 + rr;
            x3tb[(size_t)(bid >> 2) * 16384 + (size_t)o * 64 + ij] =
                f2bf(fmaxf(acc[mi][ni][rr] + bv, 0.f));
          }
        }
    }
    gbar(arv, rel, ++ph);

    // ---- lin split-K partials  [MFMA] ----
    {
      f4v acc[2][2];
      #pragma unroll
      for (int i = 0; i < 2; ++i)
        #pragma unroll
        for (int j = 0; j < 2; ++j) acc[i][j] = (f4v){0.f, 0.f, 0.f, 0.f};
      int nb = bid & 3, kcb = bid >> 2;
      mfma_block_gemm(x3tb + (size_t)kcb * 256, 16384,
                      linb + (size_t)nb * 64 * 16384 + (size_t)kcb * 256, 16384,
                      sh.ge.a, sh.ge.b, tid, acc);
      int lane = tid & 63, wv = tid >> 6;
      int mt = (wv & 1) << 5, nt = (wv >> 1) << 5;
      int fr = lane & 15, r4 = (lane >> 4) << 2;
      #pragma unroll
      for (int mi = 0; mi < 2; ++mi)
        #pragma unroll
        for (int ni = 0; ni < 2; ++ni) {
          int o = nb * 64 + nt + ni * 16 + fr;
          #pragma unroll
          for (int rr = 0; rr < 4; ++rr) {
            int n = mt + mi * 16 + r4 + rr;
            part[((size_t)kcb * cN + n) * cH + o] = acc[mi][ni][rr];
          }
        }
    }
    gbar(arv, rel, ++ph);

    // ---- tail: blocks 0..63, one per n ----
    if (bid < cN) {
      int n = bid;
      float* orow = out + ((size_t)(t * cN + n)) * cOW;
      float acc = lin_b[tid];
      for (int kc = 0; kc < 64; ++kc) acc += part[((size_t)(kc * cN + n)) * cH + tid];
      float sv = fmaxf(acc, 0.f);
      sh.tl.ss[tid] = sv;
      orow[1 + cAN + 1 + tid] = sv;
      __syncthreads();
      if (tid < cAN) {
        float a = actor_b[tid];
        const float* wr = actor_w + tid * cH;
        for (int h = 0; h < cH; ++h) a += wr[h] * sh.tl.ss[h];
        sh.tl.lg[tid] = a;
      }
      __syncthreads();
      if (tid < cAN) {
        float m = sh.tl.lg[0];
        for (int i = 1; i < cAN; ++i) m = fmaxf(m, sh.tl.lg[i]);
        sh.tl.dpv[tid] = expf(sh.tl.lg[tid] - m);
      }
      __syncthreads();
      if (tid < cAN) {
        float s = 0.f;
        for (int i = 0; i < cAN; ++i) s += sh.tl.dpv[i];
        float dprob = sh.tl.dpv[tid] / s;
        float nv = (tid < 5) ? 1.f : inter[((size_t)(t * cN + n)) * (cAN - 5) + (tid - 5)];
        sh.tl.nz[tid] = nv;
        sh.tl.pr[tid] = dprob * nv;
      }
      __syncthreads();
      if (tid < cAN) {
        float sp = 0.f, sn = 0.f;
        for (int i = 0; i < cAN; ++i) { sp += sh.tl.pr[i]; sn += sh.tl.nz[i]; }
        float deficit = 1.f - sp;
        float v2 = sh.tl.pr[tid] + (sh.tl.nz[tid] / fmaxf(sn, 1e-12f)) * deficit;
        sh.tl.pr[tid] = fminf(fmaxf(v2, 0.f), 1.f);
      }
      __syncthreads();
      if (tid < cAN) {
        float s = 0.f;
        for (int i = 0; i < cAN; ++i) s += sh.tl.pr[i];
        orow[1 + tid] = sh.tl.pr[tid] / fmaxf(s, 1e-12f);
      }
      int at = actions[t * cN + n];
      {
        float a = psi_b[tid];
        for (int h = 0; h < cH; ++h) a += psip[((size_t)(at * cH + h)) * cH + tid] * sh.tl.ss[h];
        sh.tl.es[tid] = a;
        sh.tl.red[tid] = a * a;
      }
      __syncthreads();
      for (int st = 128; st > 0; st >>= 1) {
        if (tid < st) sh.tl.red[tid] += sh.tl.red[tid + st];
        __syncthreads();
      }
      float enorm = sqrtf(sh.tl.red[0]);
      if (tid == 0) {
        float a = critic_b[0];
        for (int h = 0; h < cH; ++h) a += critic_w[h] * sh.tl.ss[h];
        orow[1 + cAN] = a;
        orow[0] = (float)at;
      }
      if (tid < cS) {
        const float* xr = X + ((size_t)(n * cS + tid)) * cHG;
        float dpp = 0.f, dmm = 0.f;
        for (int h = 0; h < cH; ++h) {
          float ev = sh.tl.es[h];
          dpp += ev * xr[2 + 2 * cH + h];
          dmm += ev * xr[2 + cH + h];
        }
        float cP = dpp / fmaxf(enorm * nMp[n * cS + tid], 1e-8f);
        float cM = dmm / fmaxf(enorm * nMm[n * cS + tid], 1e-8f);
        float cc = xr[0];
        float pn = psb[n * cS + tid] + cc * cP - cc * cM;
        p[n * cS + tid] = pn;
        orow[1 + cAN + 1 + cH + tid] = pn;
      }
      if (t == cT - 1) {
        __threadfence_block();
        __syncthreads();
        float* orow2 = out + (size_t)cT * cN * cOW + (size_t)n * cOW;
        orow2[tid] = orow[tid];
        if (tid + 256 < cOW) orow2[tid + 256] = orow[tid + 256];
      } else {
        __syncthreads();
        ps_r_compute(n, p, X, psb, r, sh.tl.pss, sh.tl.red64, sh.tl.mxs);
      }
    }
    gbar(arv, rel, ++ph);
  }
}

// ---------------------------------------------------------------------------
extern "C" void kernel_launch(void* const* d_in, const int* in_sizes, int n_in,
                              void* d_out, int out_size, void* d_ws, size_t ws_size,
                              hipStream_t stream) {
  const float* base     = (const float*)d_in[0];
  const float* inter    = (const float*)d_in[1];
  const float* hxs      = (const float*)d_in[2];
  const float* emb      = (const float*)d_in[3];
  const float* w_ih     = (const float*)d_in[4];
  const float* w_hh     = (const float*)d_in[5];
  const float* b_ih     = (const float*)d_in[6];
  const float* b_hh     = (const float*)d_in[7];
  const float* conv0_w  = (const float*)d_in[8];
  const float* conv0_b  = (const float*)d_in[9];
  const float* convs_w  = (const float*)d_in[10];
  const float* convs_b  = (const float*)d_in[11];
  const float* lin_w    = (const float*)d_in[12];
  const float* lin_b    = (const float*)d_in[13];
  const float* psi_w    = (const float*)d_in[14];
  const float* psi_b    = (const float*)d_in[15];
  const float* actor_w  = (const float*)d_in[16];
  const float* actor_b  = (const float*)d_in[17];
  const float* critic_w = (const float*)d_in[18];
  const float* critic_b = (const float*)d_in[19];
  const int*   subtasks = (const int*)d_in[20];
  const int*   actions  = (const int*)d_in[21];
  float* out = (float*)d_out;
  float* ws  = (float*)d_ws;

  // ---- workspace layout (floats) ----
  int*   arv   = (int*)ws;                  // 256 lines x 32 ints
  int*   rel   = (int*)ws + 8192;           // own line; region = 8448 ints
  float* gitab = ws + 8448;                 // 73,920
  float* X     = ws + 82368;                // 3,153,920
  float* hT    = ws + 3236288;              // 2 x 196*64*4 = 100,352
  float* psip  = ws + 3336640;              // 1,048,576
  float* p     = ws + 4385216;              // 4096
  float* psb   = ws + 4389312;              // 4096
  float* r     = ws + 4393408;              // 16,384
  float* nMp   = ws + 4409792;              // 4096
  float* nMm   = ws + 4413888;              // 4096
  float* part  = ws + 4417984;              // 1,048,576
  u16*   ub    = (u16*)(ws + 5466560);      // bf16 arena
  u16* w1b  = ub;                           // 65,536
  u16* w2b  = ub + 65536;                   // 65,536
  u16* linb = ub + 131072;                  // 4,194,304
  u16* x1b  = ub + 4325376;                 // 1,048,576
  u16* x2b  = ub + 5373952;                 // 1,048,576
  u16* x3tb = ub + 6422528;                 // 1,048,576

  hipMemsetAsync(arv, 0, 8448 * sizeof(int), stream);
  k_fused<<<GRID, 256, 0, stream>>>(
      base, inter, hxs, emb, w_ih, w_hh, b_ih, b_hh, conv0_w, conv0_b,
      convs_w, convs_b, lin_w, lin_b, psi_w, psi_b, actor_w, actor_b,
      critic_w, critic_b, subtasks, actions, out,
      arv, rel, gitab, X, hT, psip, p, psb, r, nMp, nMm, part,
      w1b, w2b, linb, x1b, x2b, x3tb);
}

// Round 5
// 7763.544 us; speedup vs baseline: 2.3221x; 2.3221x over previous
//
#include <hip/hip_runtime.h>
#include <math.h>

typedef unsigned short u16;
typedef short s8v __attribute__((ext_vector_type(8)));    // 8 bf16 (MFMA A/B frag)
typedef float f4v __attribute__((ext_vector_type(4)));    // MFMA C/D frag

constexpr int cH  = 256;
constexpr int cS  = 64;
constexpr int cAN = 16;
constexpr int cT  = 32;
constexpr int cN  = 64;
constexpr int cHG = 770;
constexpr int cG3 = 2310;
constexpr int cOW = 338;
constexpr int GRID = 256;
constexpr int CK   = 112;   // GRU k-chunk
constexpr int NCH  = 7;     // ceil(784/112)
constexpr int HTROWS = 196; // hT rows (k/4 groups, padded)

union Sh {
  struct { float4 hsT[28][64]; } gru;                                   // 28.7 KB
  struct { u16 a[64 * 264]; u16 b[64 * 264]; } ge;                      // 67.6 KB
  struct { float rs[256]; float bs[512]; float wt[32][260]; float w0s[32][12]; } c0;
  struct { float ss[256]; float es[256]; float red[256];
           float lg[16]; float dpv[16]; float nz[16]; float pr[16];
           float pss[64]; float red64[64]; float mxs[2]; int anynz; } tl;
};

__device__ __forceinline__ u16 f2bf(float x) {
  unsigned u = __float_as_uint(x);
  unsigned r = (u + 0x7FFFu + ((u >> 16) & 1u)) >> 16;
  return (u16)r;
}

// Fully distributed grid barrier: one private 128B arrival line AND one
// private 128B release line per block. No line is polled by >1 block.
__device__ __forceinline__ void gbar(int* arv, int* rel, int ph) {
  __syncthreads();
  if (blockIdx.x == 0) {
    int b = threadIdx.x;
    if (b > 0) {
      while (__hip_atomic_load(&arv[b * 32], __ATOMIC_RELAXED,
                               __HIP_MEMORY_SCOPE_AGENT) < ph)
        __builtin_amdgcn_s_sleep(2);
    }
    __syncthreads();
    __builtin_amdgcn_fence(__ATOMIC_ACQUIRE, "agent");
    if (b > 0)
      __hip_atomic_store(&rel[b * 32], ph, __ATOMIC_RELEASE,
                         __HIP_MEMORY_SCOPE_AGENT);
  } else {
    if (threadIdx.x == 0) {
      __hip_atomic_store(&arv[blockIdx.x * 32], ph, __ATOMIC_RELEASE,
                         __HIP_MEMORY_SCOPE_AGENT);
      while (__hip_atomic_load(&rel[blockIdx.x * 32], __ATOMIC_RELAXED,
                               __HIP_MEMORY_SCOPE_AGENT) < ph)
        __builtin_amdgcn_s_sleep(2);
      __builtin_amdgcn_fence(__ATOMIC_ACQUIRE, "agent");
    }
  }
  __syncthreads();
}

// softmax(p[n]) -> psb, r[n] = ps @ M[n]
__device__ __forceinline__ void ps_r_compute(int n, const float* p, const float* X,
                                             float* psb, float* r,
                                             float* pss, float* red, float* mxs) {
  int tid = threadIdx.x;
  if (tid < cS) red[tid] = p[n * cS + tid];
  __syncthreads();
  if (tid == 0) { float m = red[0]; for (int i = 1; i < cS; ++i) m = fmaxf(m, red[i]); mxs[0] = m; }
  __syncthreads();
  if (tid < cS) red[tid] = expf(red[tid] - mxs[0]);
  __syncthreads();
  if (tid == 0) { float s = 0.f; for (int i = 0; i < cS; ++i) s += red[i]; mxs[1] = s; }
  __syncthreads();
  if (tid < cS) { pss[tid] = red[tid] / mxs[1]; psb[n * cS + tid] = pss[tid]; }
  __syncthreads();
  float acc = 0.f;
  for (int s2 = 0; s2 < cS; ++s2)
    acc += pss[s2] * X[((size_t)(n * cS + s2)) * cHG + 2 + tid];
  r[n * cH + tid] = acc;
}

// 64x64x256 bf16 MFMA tile: stages A,B rows (K contiguous) then 8 k-steps.
__device__ __forceinline__ void mfma_block_gemm(const u16* Ab, size_t lda,
                                                const u16* Bb, size_t ldb,
                                                u16* AsL, u16* BsL, int tid,
                                                f4v acc[2][2]) {
  #pragma unroll
  for (int q = 0; q < 8; ++q) {
    int idx = q * 256 + tid, row = idx >> 5, c = idx & 31;
    *(s8v*)&AsL[row * 264 + c * 8] = *(const s8v*)(Ab + (size_t)row * lda + c * 8);
    *(s8v*)&BsL[row * 264 + c * 8] = *(const s8v*)(Bb + (size_t)row * ldb + c * 8);
  }
  __syncthreads();
  int lane = tid & 63, wv = tid >> 6;
  int mt = (wv & 1) << 5, nt = (wv >> 1) << 5;
  int fr = lane & 15, kg = (lane >> 4) << 3;
  #pragma unroll
  for (int ks = 0; ks < 8; ++ks) {
    int ko = ks * 32 + kg;
    s8v a0 = *(const s8v*)&AsL[(mt + fr) * 264 + ko];
    s8v a1 = *(const s8v*)&AsL[(mt + 16 + fr) * 264 + ko];
    s8v b0 = *(const s8v*)&BsL[(nt + fr) * 264 + ko];
    s8v b1 = *(const s8v*)&BsL[(nt + 16 + fr) * 264 + ko];
    acc[0][0] = __builtin_amdgcn_mfma_f32_16x16x32_bf16(a0, b0, acc[0][0], 0, 0, 0);
    acc[0][1] = __builtin_amdgcn_mfma_f32_16x16x32_bf16(a0, b1, acc[0][1], 0, 0, 0);
    acc[1][0] = __builtin_amdgcn_mfma_f32_16x16x32_bf16(a1, b0, acc[1][0], 0, 0, 0);
    acc[1][1] = __builtin_amdgcn_mfma_f32_16x16x32_bf16(a1, b1, acc[1][1], 0, 0, 0);
  }
}

__global__ __launch_bounds__(256, 2) void k_fused(
    const float* __restrict__ base, const float* __restrict__ inter,
    const float* __restrict__ hxs, const float* __restrict__ emb,
    const float* __restrict__ w_ih, const float* __restrict__ w_hh,
    const float* __restrict__ b_ih, const float* __restrict__ b_hh,
    const float* __restrict__ conv0_w, const float* __restrict__ conv0_b,
    const float* __restrict__ convs_w, const float* __restrict__ convs_b,
    const float* __restrict__ lin_w, const float* __restrict__ lin_b,
    const float* __restrict__ psi_w, const float* __restrict__ psi_b,
    const float* __restrict__ actor_w, const float* __restrict__ actor_b,
    const float* __restrict__ critic_w, const float* __restrict__ critic_b,
    const int* __restrict__ subtasks, const int* __restrict__ actions,
    float* __restrict__ out,
    int* arv, int* rel,
    float* __restrict__ gitab, float* __restrict__ X, float* __restrict__ hT,
    float* __restrict__ psip,
    float* __restrict__ p, float* __restrict__ psb, float* __restrict__ r,
    float* __restrict__ nMp, float* __restrict__ nMm,
    float* __restrict__ part,
    u16* __restrict__ w1b, u16* __restrict__ w2b, u16* __restrict__ linb,
    u16* __restrict__ x1b, u16* __restrict__ x2b, u16* __restrict__ x3tb) {
  __shared__ Sh sh;
  const int bid = blockIdx.x, tid = threadIdx.x;
  int ph = 0;

  // ---------------- phase 0: gitab, psip, bf16 weight converts ----------------
  for (int work = bid; work < 320; work += GRID) {
    int v = work / 10, jb = work % 10;
    int j = jb * 256 + tid;
    if (j < cG3) {
      float acc = b_ih[j];
      const float* wr = w_ih + (size_t)j * cH;
      const float* er = emb + (size_t)v * cH;
      #pragma unroll 8
      for (int h = 0; h < cH; ++h) acc += wr[h] * er[h];
      gitab[(size_t)v * cG3 + j] = acc;
    }
  }
  #pragma unroll
  for (int q = 0; q < 16; ++q) {
    int idx = bid * 4096 + q * 256 + tid;
    int a = idx >> 16, h = (idx >> 8) & 255, o = idx & 255;
    psip[idx] = psi_w[((size_t)o * cH + h) * cAN + a];
  }
  for (int i = bid * 256 + tid; i < 131072; i += GRID * 256) {
    w1b[i] = f2bf(convs_w[i]);
  }
  for (int i = bid * 256 + tid; i < 131072; i += GRID * 256) {
    if (i >= 65536) w2b[i - 65536] = f2bf(convs_w[i]);
  }
  for (int it = 0; it < 64; ++it) {
    size_t i = (size_t)bid * 16384 + it * 256 + tid;
    linb[i] = f2bf(lin_w[i]);
  }
  gbar(arv, rel, ++ph);

  // ---------------- phase 1: GRU (weights via scalar loads, hsT conflict-free) ---
  {
    int m = tid & 63;
    int klu = __builtin_amdgcn_readfirstlane(tid >> 6);   // wave-uniform
    int krow = bid * 4 + klu;
    bool act = (bid < 193) && (krow < cHG);
    int krs = (krow < cHG) ? krow : 0;
    const float* w0 = w_hh + (size_t)krs * cHG;
    const float* w1 = w_hh + (size_t)(cHG + krs) * cHG;
    const float* w2 = w_hh + (size_t)(2 * cHG + krs) * cHG;
    for (int s = 0; s < cS; ++s) {
      float accr = 0.f, accz = 0.f, accn = 0.f;
      if (bid < 193 && s > 0) {
        const float4* hTr = (const float4*)(hT + (size_t)((s - 1) & 1) * (HTROWS * 64 * 4));
        for (int c = 0; c < NCH; ++c) {
          #pragma unroll
          for (int q = 0; q < 7; ++q) {
            int idx = q * 256 + tid;
            int j = idx >> 6, mm = idx & 63;
            sh.gru.hsT[j][mm] = hTr[(c * 28 + j) * 64 + mm];
          }
          __syncthreads();
          int kc = c * CK;
          if (c < 6) {
            #pragma unroll 7
            for (int j = 0; j < 28; ++j) {
              float4 h4 = sh.gru.hsT[j][m];
              float4 w0v = *(const float4*)(w0 + kc + 4 * j);
              float4 w1v = *(const float4*)(w1 + kc + 4 * j);
              float4 w2v = *(const float4*)(w2 + kc + 4 * j);
              accr += h4.x * w0v.x + h4.y * w0v.y + h4.z * w0v.z + h4.w * w0v.w;
              accz += h4.x * w1v.x + h4.y * w1v.y + h4.z * w1v.z + h4.w * w1v.w;
              accn += h4.x * w2v.x + h4.y * w2v.y + h4.z * w2v.z + h4.w * w2v.w;
            }
          } else {
            #pragma unroll 6
            for (int j = 0; j < 24; ++j) {
              float4 h4 = sh.gru.hsT[j][m];
              float4 w0v = *(const float4*)(w0 + kc + 4 * j);
              float4 w1v = *(const float4*)(w1 + kc + 4 * j);
              float4 w2v = *(const float4*)(w2 + kc + 4 * j);
              accr += h4.x * w0v.x + h4.y * w0v.y + h4.z * w0v.z + h4.w * w0v.w;
              accz += h4.x * w1v.x + h4.y * w1v.y + h4.z * w1v.z + h4.w * w1v.w;
              accn += h4.x * w2v.x + h4.y * w2v.y + h4.z * w2v.z + h4.w * w2v.w;
            }
            float4 h4 = sh.gru.hsT[24][m];
            accr += h4.x * w0[768] + h4.y * w0[769];
            accz += h4.x * w1[768] + h4.y * w1[769];
            accn += h4.x * w2[768] + h4.y * w2[769];
          }
          __syncthreads();
        }
      }
      if (act) {
        int v = subtasks[m * cS + s];
        const float* git = gitab + (size_t)v * cG3;
        float rg = 1.f / (1.f + expf(-(git[krow] + accr + b_hh[krow])));
        float zg = 1.f / (1.f + expf(-(git[cHG + krow] + accz + b_hh[cHG + krow])));
        float ng = tanhf(git[2 * cHG + krow] + rg * (accn + b_hh[2 * cHG + krow]));
        float hp = (s > 0) ? X[((size_t)(m * cS + s - 1)) * cHG + krow] : 0.f;
        float h2 = (1.f - zg) * ng + zg * hp;
        X[((size_t)(m * cS + s)) * cHG + krow] = h2;
        hT[(size_t)(s & 1) * (HTROWS * 64 * 4) + ((krow >> 2) * 64 + m) * 4 + (krow & 3)] = h2;
      }
      gbar(arv, rel, ++ph);
    }
  }

  // ---------------- phase 2: p_init, norms, ps0/r0 ----------------
  if (bid < cN) {
    int n = bid;
    if (tid == 0) sh.tl.anynz = 0;
    __syncthreads();
    int nz = (hxs[n * cOW + tid] != 0.f) ? 1 : 0;
    if (tid + 256 < cOW) nz |= (hxs[n * cOW + tid + 256] != 0.f) ? 1 : 0;
    if (nz) sh.tl.anynz = 1;
    __syncthreads();
    bool newep = (sh.tl.anynz == 0);
    if (tid < cS) {
      const float* xr = X + ((size_t)(n * cS + tid)) * cHG;
      float p0 = xr[1];
      p[n * cS + tid] = newep ? p0 : hxs[n * cOW + 1 + cAN + 1 + cH + tid];
      float sp = 0.f, sm = 0.f;
      for (int h = 0; h < cH; ++h) {
        float vp = xr[2 + 2 * cH + h]; sp += vp * vp;
        float vm = xr[2 + cH + h];     sm += vm * vm;
      }
      nMp[n * cS + tid] = sqrtf(sp);
      nMm[n * cS + tid] = sqrtf(sm);
    }
    __syncthreads();
    ps_r_compute(n, p, X, psb, r, sh.tl.pss, sh.tl.red64, sh.tl.mxs);
  }
  gbar(arv, rel, ++ph);

  // ---------------- phase 3: T-scan ----------------
  for (int t = 0; t < cT; ++t) {
    // ---- conv0 (factorized, fp32 compute, bf16 output) ----
    {
      int obq = bid >> 6, n = bid & 63;
      sh.c0.rs[tid] = r[n * cH + tid];
      sh.c0.bs[tid]       = base[((size_t)(t * cN + n)) * 512 + tid];
      sh.c0.bs[tid + 256] = base[((size_t)(t * cN + n)) * 512 + tid + 256];
      __syncthreads();
      for (int half = 0; half < 2; ++half) {
        int ob = obq * 2 + half;
        int o_l = tid >> 3, d = tid & 7;
        float acc = 0.f;
        for (int hc = 0; hc < 8; ++hc) {
          #pragma unroll
          for (int q = 0; q < 8; ++q) {
            int idx = q * 256 + tid;
            int row = idx >> 6, c4 = (idx & 63) * 4;
            *(float4*)&sh.c0.wt[row][c4] =
                *(const float4*)(conv0_w + (size_t)(ob * 32 + row) * 2048 + hc * 256 + c4);
          }
          __syncthreads();
          #pragma unroll
          for (int h2 = 0; h2 < 32; ++h2)
            acc += sh.c0.wt[o_l][h2 * 8 + d] * sh.c0.rs[hc * 32 + h2];
          __syncthreads();
        }
        sh.c0.w0s[o_l][d] = acc;
        __syncthreads();
        int o2 = tid & 31, ijg = tid >> 5;
        float bias = conv0_b[ob * 32 + o2];
        #pragma unroll
        for (int q = 0; q < 8; ++q) {
          int ij = ijg * 8 + q;
          float v = bias;
          #pragma unroll
          for (int d2 = 0; d2 < 8; ++d2) v += sh.c0.w0s[o2][d2] * sh.c0.bs[d2 * 64 + ij];
          x1b[((size_t)(n * 64 + ij)) * cH + ob * 32 + o2] = f2bf(fmaxf(v, 0.f));
        }
        __syncthreads();
      }
    }
    gbar(arv, rel, ++ph);

    // ---- x2 = relu(x1 @ W1^T + b1)  [MFMA] ----
    {
      f4v acc[2][2];
      #pragma unroll
      for (int i = 0; i < 2; ++i)
        #pragma unroll
        for (int j = 0; j < 2; ++j) acc[i][j] = (f4v){0.f, 0.f, 0.f, 0.f};
      mfma_block_gemm(x1b + (size_t)(bid >> 2) * 64 * 256, 256,
                      w1b + (size_t)(bid & 3) * 64 * 256, 256,
                      sh.ge.a, sh.ge.b, tid, acc);
      int lane = tid & 63, wv = tid >> 6;
      int mt = (wv & 1) << 5, nt = (wv >> 1) << 5;
      int fr = lane & 15, r4 = (lane >> 4) << 2;
      #pragma unroll
      for (int mi = 0; mi < 2; ++mi)
        #pragma unroll
        for (int ni = 0; ni < 2; ++ni) {
          int col = (bid & 3) * 64 + nt + ni * 16 + fr;
          float bv = convs_b[col];
          #pragma unroll
          for (int rr = 0; rr < 4; ++rr) {
            int row = (bid >> 2) * 64 + mt + mi * 16 + r4 + rr;
            x2b[(size_t)row * 256 + col] = f2bf(fmaxf(acc[mi][ni][rr] + bv, 0.f));
          }
        }
    }
    gbar(arv, rel, ++ph);

    // ---- x3t = relu(x2 @ W2^T + b2), transposed write  [MFMA] ----
    {
      f4v acc[2][2];
      #pragma unroll
      for (int i = 0; i < 2; ++i)
        #pragma unroll
        for (int j = 0; j < 2; ++j) acc[i][j] = (f4v){0.f, 0.f, 0.f, 0.f};
      mfma_block_gemm(x2b + (size_t)(bid >> 2) * 64 * 256, 256,
                      w2b + (size_t)(bid & 3) * 64 * 256, 256,
                      sh.ge.a, sh.ge.b, tid, acc);
      int lane = tid & 63, wv = tid >> 6;
      int mt = (wv & 1) << 5, nt = (wv >> 1) << 5;
      int fr = lane & 15, r4 = (lane >> 4) << 2;
      #pragma unroll
      for (int mi = 0; mi < 2; ++mi)
        #pragma unroll
        for (int ni = 0; ni < 2; ++ni) {
          int o = (bid & 3) * 64 + nt + ni * 16 + fr;
          float bv = convs_b[256 + o];
          #pragma unroll
          for (int rr = 0; rr < 4; ++rr) {
            int ij = mt + mi * 16 + r4 + rr;
            x3tb[(size_t)(bid >> 2) * 16384 + (size_t)o * 64 + ij] =
                f2bf(fmaxf(acc[mi][ni][rr] + bv, 0.f));
          }
        }
    }
    gbar(arv, rel, ++ph);

    // ---- lin split-K partials  [MFMA] ----
    {
      f4v acc[2][2];
      #pragma unroll
      for (int i = 0; i < 2; ++i)
        #pragma unroll
        for (int j = 0; j < 2; ++j) acc[i][j] = (f4v){0.f, 0.f, 0.f, 0.f};
      int nb = bid & 3, kcb = bid >> 2;
      mfma_block_gemm(x3tb + (size_t)kcb * 256, 16384,
                      linb + (size_t)nb * 64 * 16384 + (size_t)kcb * 256, 16384,
                      sh.ge.a, sh.ge.b, tid, acc);
      int lane = tid & 63, wv = tid >> 6;
      int mt = (wv & 1) << 5, nt = (wv >> 1) << 5;
      int fr = lane & 15, r4 = (lane >> 4) << 2;
      #pragma unroll
      for (int mi = 0; mi < 2; ++mi)
        #pragma unroll
        for (int ni = 0; ni < 2; ++ni) {
          int o = nb * 64 + nt + ni * 16 + fr;
          #pragma unroll
          for (int rr = 0; rr < 4; ++rr) {
            int n = mt + mi * 16 + r4 + rr;
            part[((size_t)kcb * cN + n) * cH + o] = acc[mi][ni][rr];
          }
        }
    }
    gbar(arv, rel, ++ph);

    // ---- tail: blocks 0..63, one per n ----
    if (bid < cN) {
      int n = bid;
      float* orow = out + ((size_t)(t * cN + n)) * cOW;
      float acc = lin_b[tid];
      for (int kc = 0; kc < 64; ++kc) acc += part[((size_t)(kc * cN + n)) * cH + tid];
      float sv = fmaxf(acc, 0.f);
      sh.tl.ss[tid] = sv;
      orow[1 + cAN + 1 + tid] = sv;
      __syncthreads();
      if (tid < cAN) {
        float a = actor_b[tid];
        const float* wr = actor_w + tid * cH;
        for (int h = 0; h < cH; ++h) a += wr[h] * sh.tl.ss[h];
        sh.tl.lg[tid] = a;
      }
      __syncthreads();
      if (tid < cAN) {
        float m = sh.tl.lg[0];
        for (int i = 1; i < cAN; ++i) m = fmaxf(m, sh.tl.lg[i]);
        sh.tl.dpv[tid] = expf(sh.tl.lg[tid] - m);
      }
      __syncthreads();
      if (tid < cAN) {
        float s = 0.f;
        for (int i = 0; i < cAN; ++i) s += sh.tl.dpv[i];
        float dprob = sh.tl.dpv[tid] / s;
        float nv = (tid < 5) ? 1.f : inter[((size_t)(t * cN + n)) * (cAN - 5) + (tid - 5)];
        sh.tl.nz[tid] = nv;
        sh.tl.pr[tid] = dprob * nv;
      }
      __syncthreads();
      if (tid < cAN) {
        float sp = 0.f, sn = 0.f;
        for (int i = 0; i < cAN; ++i) { sp += sh.tl.pr[i]; sn += sh.tl.nz[i]; }
        float deficit = 1.f - sp;
        float v2 = sh.tl.pr[tid] + (sh.tl.nz[tid] / fmaxf(sn, 1e-12f)) * deficit;
        sh.tl.pr[tid] = fminf(fmaxf(v2, 0.f), 1.f);
      }
      __syncthreads();
      if (tid < cAN) {
        float s = 0.f;
        for (int i = 0; i < cAN; ++i) s += sh.tl.pr[i];
        orow[1 + tid] = sh.tl.pr[tid] / fmaxf(s, 1e-12f);
      }
      int at = actions[t * cN + n];
      {
        float a = psi_b[tid];
        for (int h = 0; h < cH; ++h) a += psip[((size_t)(at * cH + h)) * cH + tid] * sh.tl.ss[h];
        sh.tl.es[tid] = a;
        sh.tl.red[tid] = a * a;
      }
      __syncthreads();
      for (int st = 128; st > 0; st >>= 1) {
        if (tid < st) sh.tl.red[tid] += sh.tl.red[tid + st];
        __syncthreads();
      }
      float enorm = sqrtf(sh.tl.red[0]);
      if (tid == 0) {
        float a = critic_b[0];
        for (int h = 0; h < cH; ++h) a += critic_w[h] * sh.tl.ss[h];
        orow[1 + cAN] = a;
        orow[0] = (float)at;
      }
      if (tid < cS) {
        const float* xr = X + ((size_t)(n * cS + tid)) * cHG;
        float dpp = 0.f, dmm = 0.f;
        for (int h = 0; h < cH; ++h) {
          float ev = sh.tl.es[h];
          dpp += ev * xr[2 + 2 * cH + h];
          dmm += ev * xr[2 + cH + h];
        }
        float cP = dpp / fmaxf(enorm * nMp[n * cS + tid], 1e-8f);
        float cM = dmm / fmaxf(enorm * nMm[n * cS + tid], 1e-8f);
        float cc = xr[0];
        float pn = psb[n * cS + tid] + cc * cP - cc * cM;
        p[n * cS + tid] = pn;
        orow[1 + cAN + 1 + cH + tid] = pn;
      }
      if (t == cT - 1) {
        __threadfence_block();
        __syncthreads();
        float* orow2 = out + (size_t)cT * cN * cOW + (size_t)n * cOW;
        orow2[tid] = orow[tid];
        if (tid + 256 < cOW) orow2[tid + 256] = orow[tid + 256];
      } else {
        __syncthreads();
        ps_r_compute(n, p, X, psb, r, sh.tl.pss, sh.tl.red64, sh.tl.mxs);
      }
    }
    gbar(arv, rel, ++ph);
  }
}

// ---------------------------------------------------------------------------
extern "C" void kernel_launch(void* const* d_in, const int* in_sizes, int n_in,
                              void* d_out, int out_size, void* d_ws, size_t ws_size,
                              hipStream_t stream) {
  const float* base     = (const float*)d_in[0];
  const float* inter    = (const float*)d_in[1];
  const float* hxs      = (const float*)d_in[2];
  const float* emb      = (const float*)d_in[3];
  const float* w_ih     = (const float*)d_in[4];
  const float* w_hh     = (const float*)d_in[5];
  const float* b_ih     = (const float*)d_in[6];
  const float* b_hh     = (const float*)d_in[7];
  const float* conv0_w  = (const float*)d_in[8];
  const float* conv0_b  = (const float*)d_in[9];
  const float* convs_w  = (const float*)d_in[10];
  const float* convs_b  = (const float*)d_in[11];
  const float* lin_w    = (const float*)d_in[12];
  const float* lin_b    = (const float*)d_in[13];
  const float* psi_w    = (const float*)d_in[14];
  const float* psi_b    = (const float*)d_in[15];
  const float* actor_w  = (const float*)d_in[16];
  const float* actor_b  = (const float*)d_in[17];
  const float* critic_w = (const float*)d_in[18];
  const float* critic_b = (const float*)d_in[19];
  const int*   subtasks = (const int*)d_in[20];
  const int*   actions  = (const int*)d_in[21];
  float* out = (float*)d_out;
  float* ws  = (float*)d_ws;

  // ---- workspace layout (floats) ----
  int*   arv   = (int*)ws;                  // 256 lines x 32 ints
  int*   rel   = (int*)ws + 8192;           // 256 lines x 32 ints
  float* gitab = ws + 16384;                // 73,920
  float* X     = ws + 90304;                // 3,153,920
  float* hT    = ws + 3244224;              // 2 x 196*64*4 = 100,352
  float* psip  = ws + 3344576;              // 1,048,576
  float* p     = ws + 4393152;              // 4096
  float* psb   = ws + 4397248;              // 4096
  float* r     = ws + 4401344;              // 16,384
  float* nMp   = ws + 4417728;              // 4096
  float* nMm   = ws + 4421824;              // 4096
  float* part  = ws + 4425920;              // 1,048,576
  u16*   ub    = (u16*)(ws + 5474496);      // bf16 arena
  u16* w1b  = ub;                           // 65,536
  u16* w2b  = ub + 65536;                   // 65,536
  u16* linb = ub + 131072;                  // 4,194,304
  u16* x1b  = ub + 4325376;                 // 1,048,576
  u16* x2b  = ub + 5373952;                 // 1,048,576
  u16* x3tb = ub + 6422528;                 // 1,048,576

  (void)hipMemsetAsync(arv, 0, 16384 * sizeof(int), stream);
  k_fused<<<GRID, 256, 0, stream>>>(
      base, inter, hxs, emb, w_ih, w_hh, b_ih, b_hh, conv0_w, conv0_b,
      convs_w, convs_b, lin_w, lin_b, psi_w, psi_b, actor_w, actor_b,
      critic_w, critic_b, subtasks, actions, out,
      arv, rel, gitab, X, hT, psip, p, psb, r, nMp, nMm, part,
      w1b, w2b, linb, x1b, x2b, x3tb);
}